// Round 15
// baseline (245.867 us; speedup 1.0000x reference)
//
#include <hip/hip_runtime.h>
#include <math.h>

// ---------------------------------------------------------------------------
// STPGCN forward. fp32 I/O, bf16 MFMA internal, fp32 accumulate.
// B=4 T=12 V=512 C=64 d=8 TS=3 P=12 L=4, BETA=2.
// R15 = R14 (champion: 237.6us) + two changes:
//  (a) agg 2D XCD swizzle: bid = ((k*4+mt)*3 + nt%3)*8 + (b*2 + nt/3).
//      Each XCD's 36 blocks cover one (b, nt-triple): A tiles reused 3x,
//      B tiles 12x within one L2 -> A+B HBM fetch ~15MB/layer (was ~25+).
//  (b) reduce folded into glu1cat (12-t fp32 sum in-register, bit-identical);
//      kills 1 launch + 2MB yB round trip.
// Laws learned: cross-block sync (fence/atomic/barrier) costs more than a
// launch boundary (R11 446us, R13 401us); bundles unattributable (R5/R12).
// ---------------------------------------------------------------------------

typedef unsigned short u16;
typedef __attribute__((ext_vector_type(8))) short short8;
typedef __attribute__((ext_vector_type(4))) float f32x4;
typedef __attribute__((ext_vector_type(8))) unsigned short u16x8;
typedef __attribute__((ext_vector_type(4))) unsigned short u16x4;

#define MFMA16(a, b, c) __builtin_amdgcn_mfma_f32_16x16x32_bf16((a), (b), (c), 0, 0, 0)

__device__ __forceinline__ float b2f(u16 u) {
  union { unsigned int i; float f; } x; x.i = ((unsigned int)u) << 16; return x.f;
}
__device__ __forceinline__ u16 f2b(float f) {
  union { float f; unsigned int i; } x; x.f = f;
  unsigned int r = x.i + 0x7FFFu + ((x.i >> 16) & 1u);
  return (u16)(r >> 16);
}
__device__ __forceinline__ void ld8f(const float* __restrict__ p, float* f) {
  f32x4 a = *(const f32x4*)p;
  f32x4 b = *(const f32x4*)(p + 4);
  #pragma unroll
  for (int i = 0; i < 4; ++i) { f[i] = a[i]; f[4 + i] = b[i]; }
}
__device__ __forceinline__ float gcf(const float* e, const float* __restrict__ mu,
                                     const float* __restrict__ sg) {
  float s = 0.f;
  #pragma unroll
  for (int i = 0; i < 8; ++i) {
    float dm = e[i] - mu[i];
    s += dm * dm * sg[i] * sg[i];
  }
  return -0.5f * s;
}
__device__ __forceinline__ float sigm(float v) { return 1.0f / (1.0f + expf(-v)); }

// ---------------------------------------------------------------------------
// prep (R14-identical)
// ---------------------------------------------------------------------------
__global__ __launch_bounds__(256) void prep_kernel(
    const float* __restrict__ x, const float* __restrict__ sape,
    const float* __restrict__ tape, const float* __restrict__ srpe,
    const float* __restrict__ trpe, const float* __restrict__ Wi,
    const float* __restrict__ bi, const float* __restrict__ gmu,
    const float* __restrict__ gsg, const float* __restrict__ Wg,
    const float* __restrict__ bg, const float* __restrict__ Wsp,
    const float* __restrict__ Wtp, const float* __restrict__ fsw,
    const float* __restrict__ mask,
    const float* __restrict__ g1w, const float* __restrict__ gw,
    const float* __restrict__ ow,
    u16* __restrict__ hT0, u16* __restrict__ Abf,
    float* __restrict__ spb, float* __restrict__ tpb,
    u16* __restrict__ fswT, u16* __restrict__ WgT, float* __restrict__ ev,
    u16* __restrict__ g1wB, u16* __restrict__ gwB, u16* __restrict__ owB) {
  const int tid = threadIdx.x;
  int bid = blockIdx.x;

  if (bid < 768) {  // h0 -> hT0[b][t][c][i]
    int gid = bid * 256 + tid;                 // 196608 items
    int i8 = gid & 63, c = (gid >> 6) & 63, bt = gid >> 12;
    float xv[8];
    ld8f(&x[bt * 512 + i8 * 8], xv);
    float wic = Wi[c], bic = bi[c];
    u16x8 hv;
    #pragma unroll
    for (int ii = 0; ii < 8; ++ii) hv[ii] = f2b(xv[ii] * wic + bic);
    *(u16x8*)&hT0[gid * 8] = hv;
    return;
  }
  bid -= 768;
  if (bid < 1024) {  // Abf: thread per (j,i); expbase for 4 l's, then x mask
    int gid = bid * 256 + tid;                 // 262144
    int i = gid & 511, j = gid >> 9;
    float fi[8], fj[8], fr[8];
    ld8f(sape + i * 8, fi);
    ld8f(sape + j * 8, fj);
    ld8f(srpe + ((size_t)i * 512 + j) * 8, fr);
    u16 eb[4];
    #pragma unroll
    for (int l = 0; l < 4; ++l) {
      const float* mub = gmu + l * 48;
      const float* sgb = gsg + l * 48;
      float s = gcf(fi, mub + 0, sgb + 0)
              + gcf(fj, mub + 8, sgb + 8)
              + gcf(fr, mub + 32, sgb + 32);
      eb[l] = f2b(expf(s));
    }
    #pragma unroll
    for (int b = 0; b < 4; ++b)
      #pragma unroll
      for (int k = 0; k < 3; ++k) {
        float mv = mask[((size_t)(b * 512 + j)) * 1536 + k * 512 + i];
        u16 m = (mv != 0.f) ? (u16)0xFFFFu : (u16)0;
        #pragma unroll
        for (int l = 0; l < 4; ++l)
          Abf[((size_t)((l * 4 + b) * 512 + j)) * 1536 + k * 512 + i] = eb[l] & m;
      }
    return;
  }
  bid -= 1024;
  if (bid < 1024) {  // spb[l][j][o] = sape[j]·Wsp[l][:,o]
    int gid = bid * 256 + tid;                 // 262144
    int o = gid & 127, j = (gid >> 7) & 511, l = gid >> 16;
    float s = 0.f;
    #pragma unroll
    for (int dd = 0; dd < 8; ++dd)
      s += sape[j * 8 + dd] * Wsp[(l * 8 + dd) * 128 + o];
    spb[gid] = s;
    return;
  }
  bid -= 1024;
  if (bid < 96) {  // tpb[l][bt][o] = bg[l][o] + tape[bt]·Wtp[l][:,o]
    int gid = bid * 256 + tid;                 // 24576
    int o = gid & 127, bt = (gid >> 7) % 48, l = gid / 6144;
    float s = bg[l * 128 + o];
    #pragma unroll
    for (int dd = 0; dd < 8; ++dd)
      s += tape[bt * 8 + dd] * Wtp[(l * 8 + dd) * 128 + o];
    tpb[gid] = s;
    return;
  }
  bid -= 96;
  if (bid < 768) {  // fswT[l][o][t*64+c] = fs_w[l][o][c][t]
    int gid = bid * 256 + tid;                 // 196608
    int kidx = gid % 768, rest = gid / 768;
    int o = rest & 63, l = rest >> 6;
    int c = kidx & 63, tt = kidx >> 6;
    fswT[gid] = f2b(fsw[((l * 64 + o) * 64 + c) * 12 + tt]);
    return;
  }
  bid -= 768;
  if (bid < 128) {  // WgT[l][o][c] = Wg[l][c][o]
    int gid = bid * 256 + tid;                 // 32768
    int c = gid & 63, o = (gid >> 6) & 127, l = gid >> 13;
    WgT[gid] = f2b(Wg[(l * 64 + c) * 128 + o]);
    return;
  }
  bid -= 128;
  if (bid < 3) {  // ev[l][bt][k]
    int gid = bid * 256 + tid;
    if (gid < 576) {
      int k = gid % 3, t = (gid / 3) % 12, b = (gid / 36) % 4, l = gid / 144;
      const float* mub = gmu + l * 48;
      const float* sgb = gsg + l * 48;
      float e2[8], e3[8], e5[8];
      ld8f(tape + (b * 12 + t) * 8, e2);
      int tp = t + k - 2;
      if (tp >= 0) ld8f(tape + (b * 12 + tp) * 8, e3);
      else {
        #pragma unroll
        for (int ii = 0; ii < 8; ++ii) e3[ii] = 0.f;
      }
      ld8f(trpe + k * 8, e5);
      float s = gcf(e2, mub + 16, sgb + 16)
              + gcf(e3, mub + 24, sgb + 24)
              + gcf(e5, mub + 40, sgb + 40);
      ev[gid] = expf(s);
    }
    return;
  }
  bid -= 3;
  if (bid < 128) {  // g1wB
    int gid = bid * 256 + tid;
    g1wB[gid] = f2b(g1w[gid]);
    return;
  }
  bid -= 128;
  if (bid < 512) {  // gwB
    int gid = bid * 256 + tid;
    gwB[gid] = f2b(gw[gid]);
    return;
  }
  bid -= 512;
  {  // owB
    int gid = bid * 256 + tid;
    if (gid < 3072) owB[gid] = f2b(ow[gid]);
  }
}

// ---------------------------------------------------------------------------
// agg: G[b,k,j,t'*64+c] = sum_i Abf_l[b,j,k*512+i]*hT[b,t',c,i]
// grid 288. R15 decode: bid = ((k*4+mt)*3 + nt%3)*8 + (b*2 + nt/3).
// Each XCD (bid%8) covers one (b, nt-triple): its 36 blocks reuse 12 A tiles
// (3x) and 3 B tiles (12x) entirely within one L2.
// ---------------------------------------------------------------------------
__global__ __launch_bounds__(256) void agg_kernel(
    const u16* __restrict__ Abfl, const u16* __restrict__ hT,
    u16* __restrict__ G) {
  __shared__ u16 As[128][72];
  __shared__ u16 Bs[128][72];
  const int tid = threadIdx.x, wid = tid >> 6, lane = tid & 63;
  const int l16 = lane & 15, quad = lane >> 4;
  const int bid = blockIdx.x;
  const int xcd = bid & 7;
  const int b   = xcd >> 1;
  const int ntg = xcd & 1;
  const int rest = bid >> 3;        // 0..35
  const int ntr = rest % 3;
  const int km  = rest / 3;         // 0..11
  const int mt  = km & 3;
  const int k   = km >> 2;
  const int nt  = ntg * 3 + ntr;
  const int wm = wid >> 1, wn = wid & 1;

  const u16* Arow0 = Abfl + ((size_t)(b * 512 + mt * 128)) * 1536 + k * 512;
  f32x4 acc[4][4] = {};

  for (int it = 0; it < 8; ++it) {
    const int i0 = it * 64;
    #pragma unroll
    for (int s = 0; s < 4; ++s) {
      int idx = s * 256 + tid;
      int r = idx >> 3, ch = (idx & 7) * 8;
      *(u16x8*)&As[r][ch] = *(const u16x8*)&Arow0[(size_t)r * 1536 + i0 + ch];
      int tp = nt * 2 + (r >> 6), c = r & 63;
      *(u16x8*)&Bs[r][ch] =
          *(const u16x8*)&hT[((size_t)((b * 12 + tp) * 64 + c)) * 512 + i0 + ch];
    }
    __syncthreads();
    #pragma unroll
    for (int ks = 0; ks < 2; ++ks) {
      short8 af[4], bf[4];
      #pragma unroll
      for (int mb = 0; mb < 4; ++mb)
        af[mb] = *(const short8*)&As[wm * 64 + mb * 16 + l16][ks * 32 + quad * 8];
      #pragma unroll
      for (int nb = 0; nb < 4; ++nb)
        bf[nb] = *(const short8*)&Bs[wn * 64 + nb * 16 + l16][ks * 32 + quad * 8];
      #pragma unroll
      for (int mb = 0; mb < 4; ++mb)
        #pragma unroll
        for (int nb = 0; nb < 4; ++nb)
          acc[mb][nb] = MFMA16(af[mb], bf[nb], acc[mb][nb]);
    }
    __syncthreads();
  }

  // stage C (128x128 bf16 = 32KB) in LDS over As/Bs, then coalesced write
  u16* base = &As[0][0];
  #pragma unroll
  for (int mb = 0; mb < 4; ++mb)
    #pragma unroll
    for (int nb = 0; nb < 4; ++nb) {
      int n = wn * 64 + nb * 16 + l16;
      #pragma unroll
      for (int r = 0; r < 4; ++r) {
        int m = wm * 64 + mb * 16 + quad * 4 + r;
        base[m * 128 + n] = f2b(acc[mb][nb][r]);
      }
    }
  __syncthreads();
  u16* Gp = G + ((size_t)((b * 3 + k) * 512 + mt * 128)) * 768 + nt * 128;
  #pragma unroll
  for (int s = 0; s < 8; ++s) {
    int idx = s * 256 + tid;
    int m = idx >> 4, ch = (idx & 15) * 8;
    *(u16x8*)&Gp[(size_t)m * 768 + ch] = *(const u16x8*)&base[m * 128 + ch];
  }
}

// ---------------------------------------------------------------------------
// combine (R14-identical; ypt bf16)
// ---------------------------------------------------------------------------
__global__ __launch_bounds__(256) void combine_kernel(
    const u16* __restrict__ G, const float* __restrict__ evl,
    const u16* __restrict__ WgTl, const float* __restrict__ spbl,
    const float* __restrict__ tpbl, const u16* __restrict__ fswTl,
    u16* __restrict__ hTout, u16* __restrict__ yptl) {
  __shared__ u16 aggL[128][72];
  __shared__ u16 hL[128][72];
  const int tid = threadIdx.x, wid = tid >> 6, lane = tid & 63;
  const int l16 = lane & 15, quad = lane >> 4;
  const int bid = blockIdx.x;
  const int mt = bid & 3;
  const int bt = bid >> 2;
  const int b = bt / 12, t = bt - b * 12;

  {  // combine G over k (fp32), thread = (j, 32-c half)
    int j = tid >> 1;
    int c0 = (tid & 1) * 32;
    float accv[32];
    #pragma unroll
    for (int ii = 0; ii < 32; ++ii) accv[ii] = 0.f;
    #pragma unroll
    for (int k = 0; k < 3; ++k) {
      int tp = t + k - 2;
      if (tp < 0) continue;
      float ek = evl[bt * 3 + k];
      const u16* gp = &G[((size_t)((b * 3 + k) * 512 + mt * 128 + j)) * 768 + tp * 64 + c0];
      #pragma unroll
      for (int s = 0; s < 4; ++s) {
        u16x8 gv = *(const u16x8*)&gp[s * 8];
        #pragma unroll
        for (int ii = 0; ii < 8; ++ii) accv[s * 8 + ii] += b2f(gv[ii]) * ek;
      }
    }
    #pragma unroll
    for (int s = 0; s < 4; ++s) {
      u16x8 ov;
      #pragma unroll
      for (int ii = 0; ii < 8; ++ii) ov[ii] = f2b(accv[s * 8 + ii]);
      *(u16x8*)&aggL[j][c0 + s * 8] = ov;
    }
  }
  __syncthreads();

  // phase 2: g[o,j] = sum_c WgT[o][c]*agg[j][c]
  f32x4 acc2[8][2] = {};
  #pragma unroll
  for (int ks = 0; ks < 2; ++ks) {
    short8 bf[2];
    #pragma unroll
    for (int nb = 0; nb < 2; ++nb)
      bf[nb] = *(const short8*)&aggL[wid * 32 + nb * 16 + l16][ks * 32 + quad * 8];
    #pragma unroll
    for (int mb = 0; mb < 8; ++mb) {
      short8 a = *(const short8*)&WgTl[(mb * 16 + l16) * 64 + ks * 32 + quad * 8];
      acc2[mb][0] = MFMA16(a, bf[0], acc2[mb][0]);
      acc2[mb][1] = MFMA16(a, bf[1], acc2[mb][1]);
    }
  }

  // epilogue: + spb + tpb, GLU, write hTout + hL
  #pragma unroll
  for (int mb = 0; mb < 4; ++mb) {
    int ob = mb * 16 + quad * 4;
    #pragma unroll
    for (int nb = 0; nb < 2; ++nb) {
      int jl = wid * 32 + nb * 16 + l16;
      int jg = mt * 128 + jl;
      f32x4 spl = *(const f32x4*)&spbl[jg * 128 + ob];
      f32x4 spr = *(const f32x4*)&spbl[jg * 128 + 64 + ob];
      f32x4 tpl = *(const f32x4*)&tpbl[bt * 128 + ob];
      f32x4 tpr = *(const f32x4*)&tpbl[bt * 128 + 64 + ob];
      #pragma unroll
      for (int r = 0; r < 4; ++r) {
        float vl = acc2[mb][nb][r] + spl[r] + tpl[r];
        float vr = acc2[mb + 4][nb][r] + spr[r] + tpr[r];
        u16 hb = f2b(vl * sigm(vr));
        hTout[((size_t)((b * 12 + t) * 64 + ob + r)) * 512 + jg] = hb;
        hL[jl][ob + r] = hb;
      }
    }
  }
  __syncthreads();

  // GFS partial: y_t[o][j] = sum_c fswT[o][t*64+c] * h[j][c] -> ypt bf16
  f32x4 accY[4][2] = {};
  #pragma unroll
  for (int ks = 0; ks < 2; ++ks) {
    short8 bfv[2];
    #pragma unroll
    for (int nb = 0; nb < 2; ++nb)
      bfv[nb] = *(const short8*)&hL[wid * 32 + nb * 16 + l16][ks * 32 + quad * 8];
    #pragma unroll
    for (int mb = 0; mb < 4; ++mb) {
      short8 a = *(const short8*)&fswTl[(mb * 16 + l16) * 768 + t * 64 + ks * 32 + quad * 8];
      accY[mb][0] = MFMA16(a, bfv[0], accY[mb][0]);
      accY[mb][1] = MFMA16(a, bfv[1], accY[mb][1]);
    }
  }
  #pragma unroll
  for (int mb = 0; mb < 4; ++mb)
    #pragma unroll
    for (int nb = 0; nb < 2; ++nb) {
      int j = mt * 128 + wid * 32 + nb * 16 + l16;
      #pragma unroll
      for (int r = 0; r < 4; ++r) {
        int o = mb * 16 + quad * 4 + r;
        yptl[((size_t)(bt * 64 + o)) * 512 + j] = f2b(accY[mb][nb][r]);
      }
    }
}

// ---------------------------------------------------------------------------
// glu1cat + fused t-reduce: yL[v][o] = sum_t ypt + fsb (fp32, same order as
// R14's reduce -> bit-identical); then GLU1 GEMM -> catB. grid 64.
// ---------------------------------------------------------------------------
__global__ __launch_bounds__(256) void glu1cat_kernel(
    const u16* __restrict__ ypt, const float* __restrict__ fsb,
    const u16* __restrict__ g1wB, const float* __restrict__ g1b,
    u16* __restrict__ catB) {
  __shared__ u16 yL[128][72];
  const int tid = threadIdx.x, wid = tid >> 6, lane = tid & 63;
  const int l16 = lane & 15, quad = lane >> 4;
  const int l = blockIdx.x >> 4;
  const int b = (blockIdx.x >> 2) & 3;
  const int v0 = (blockIdx.x & 3) * 128;

  {  // t-reduce: thread = (o, 32-v group)
    int o = tid & 63, sv = tid >> 6;
    float accv[32];
    float fb = fsb[l * 64 + o];
    #pragma unroll
    for (int ii = 0; ii < 32; ++ii) accv[ii] = fb;
    for (int t = 0; t < 12; ++t) {
      const u16* src = &ypt[(size_t)l * 1572864 +
                            ((size_t)((b * 12 + t) * 64 + o)) * 512 + v0 + sv * 32];
      #pragma unroll
      for (int s = 0; s < 4; ++s) {
        u16x8 v = *(const u16x8*)&src[s * 8];
        #pragma unroll
        for (int ii = 0; ii < 8; ++ii) accv[s * 8 + ii] += b2f(v[ii]);
      }
    }
    #pragma unroll
    for (int ii = 0; ii < 32; ++ii) yL[sv * 32 + ii][o] = f2b(accv[ii]);
  }
  __syncthreads();

  f32x4 acc[2][8] = {};
  #pragma unroll
  for (int ks = 0; ks < 2; ++ks) {
    short8 a0 = *(const short8*)&g1wB[l * 8192 + (wid * 16 + l16) * 64 +
                                      ks * 32 + quad * 8];
    short8 a1 = *(const short8*)&g1wB[l * 8192 + (64 + wid * 16 + l16) * 64 +
                                      ks * 32 + quad * 8];
    #pragma unroll
    for (int nb = 0; nb < 8; ++nb) {
      short8 bf = *(const short8*)&yL[nb * 16 + l16][ks * 32 + quad * 8];
      acc[0][nb] = MFMA16(a0, bf, acc[0][nb]);
      acc[1][nb] = MFMA16(a1, bf, acc[1][nb]);
    }
  }
  #pragma unroll
  for (int nb = 0; nb < 8; ++nb) {
    int v = v0 + nb * 16 + l16;
    int oc = wid * 16 + quad * 4;
    u16x4 pk;
    #pragma unroll
    for (int r = 0; r < 4; ++r) {
      float zl = acc[0][nb][r] + g1b[l * 128 + oc + r];
      float zr = acc[1][nb][r] + g1b[l * 128 + 64 + oc + r];
      pk[r] = f2b(zl * sigm(zr));
    }
    *(u16x4*)&catB[((size_t)(b * 512 + v)) * 256 + l * 64 + oc] = pk;
  }
}

// ---------------------------------------------------------------------------
// gout (R14-identical)
// ---------------------------------------------------------------------------
__global__ __launch_bounds__(256) void gout_kernel(
    const u16* __restrict__ catB, const u16* __restrict__ gwB,
    const float* __restrict__ gb, u16* __restrict__ sB) {
  __shared__ u16 cL[64][264];
  const int tid = threadIdx.x, wid = tid >> 6, lane = tid & 63;
  const int l16 = lane & 15, quad = lane >> 4;
  const int wm = wid >> 1, wn = wid & 1;
  const int b = blockIdx.x >> 6;
  const int v0 = ((blockIdx.x >> 3) & 7) * 64;
  const int cc0 = (blockIdx.x & 7) * 32;

  {
    int v = tid >> 2, seg = (tid & 3) * 64;
    const u16* src = &catB[((size_t)(b * 512 + v0 + v)) * 256 + seg];
    #pragma unroll
    for (int s = 0; s < 8; ++s)
      *(u16x8*)&cL[v][seg + s * 8] = *(const u16x8*)&src[s * 8];
  }
  __syncthreads();

  f32x4 acc[2][2] = {};
  #pragma unroll
  for (int ks = 0; ks < 8; ++ks) {
    short8 aL = *(const short8*)&gwB[(cc0 + wm * 16 + l16) * 256 +
                                     ks * 32 + quad * 8];
    short8 aH = *(const short8*)&gwB[(256 + cc0 + wm * 16 + l16) * 256 +
                                     ks * 32 + quad * 8];
    #pragma unroll
    for (int nb = 0; nb < 2; ++nb) {
      short8 bf = *(const short8*)&cL[wn * 32 + nb * 16 + l16][ks * 32 + quad * 8];
      acc[0][nb] = MFMA16(aL, bf, acc[0][nb]);
      acc[1][nb] = MFMA16(aH, bf, acc[1][nb]);
    }
  }
  #pragma unroll
  for (int nb = 0; nb < 2; ++nb) {
    int v = v0 + wn * 32 + nb * 16 + l16;
    int cc = cc0 + wm * 16 + quad * 4;
    u16x4 pk;
    #pragma unroll
    for (int r = 0; r < 4; ++r) {
      float zl = acc[0][nb][r] + gb[cc + r];
      float zr = acc[1][nb][r] + gb[256 + cc + r];
      pk[r] = f2b(zl * sigm(zr));
    }
    *(u16x4*)&sB[((size_t)(b * 512 + v)) * 256 + cc] = pk;
  }
}

// ---------------------------------------------------------------------------
// head (R14-identical)
// ---------------------------------------------------------------------------
__global__ __launch_bounds__(256) void head_kernel(
    const u16* __restrict__ sB, const u16* __restrict__ owB,
    const float* __restrict__ obv, float* __restrict__ out) {
  const int tid = threadIdx.x, wid = tid >> 6, lane = tid & 63;
  const int l16 = lane & 15, quad = lane >> 4;
  const int b = blockIdx.x >> 3;
  const int v0 = (blockIdx.x & 7) * 64;

  f32x4 acc = {};
  #pragma unroll
  for (int ks = 0; ks < 8; ++ks) {
    short8 a;
    if (l16 < 12) a = *(const short8*)&owB[l16 * 256 + ks * 32 + quad * 8];
    else {
      #pragma unroll
      for (int ii = 0; ii < 8; ++ii) a[ii] = 0;
    }
    short8 bf = *(const short8*)&sB[((size_t)(b * 512 + v0 + wid * 16 + l16)) * 256 +
                                    ks * 32 + quad * 8];
    acc = MFMA16(a, bf, acc);
  }
  #pragma unroll
  for (int r = 0; r < 4; ++r) {
    int p = quad * 4 + r;
    if (p < 12)
      out[(b * 12 + p) * 512 + v0 + wid * 16 + l16] = acc[r] + obv[p];
  }
}

// ---------------------------------------------------------------------------
extern "C" void kernel_launch(void* const* d_in, const int* in_sizes, int n_in,
                              void* d_out, int out_size, void* d_ws, size_t ws_size,
                              hipStream_t stream) {
  const float* x    = (const float*)d_in[0];
  const float* sape = (const float*)d_in[1];
  const float* tape = (const float*)d_in[2];
  const float* srpe = (const float*)d_in[3];
  const float* trpe = (const float*)d_in[4];
  const float* mask = (const float*)d_in[7];
  const float* Wi   = (const float*)d_in[8];
  const float* bi   = (const float*)d_in[9];
  const float* gmu  = (const float*)d_in[10];
  const float* gsg  = (const float*)d_in[11];
  const float* Wg   = (const float*)d_in[12];
  const float* bg   = (const float*)d_in[13];
  const float* Wsp  = (const float*)d_in[14];
  const float* Wtp  = (const float*)d_in[15];
  const float* fsw  = (const float*)d_in[16];
  const float* fsb  = (const float*)d_in[17];
  const float* g1w  = (const float*)d_in[18];
  const float* g1b  = (const float*)d_in[19];
  const float* gow  = (const float*)d_in[20];
  const float* gob  = (const float*)d_in[21];
  const float* ow   = (const float*)d_in[22];
  const float* obv  = (const float*)d_in[23];

  char* w = (char*)d_ws;
  u16*   hT_a = (u16*)(w + 0);            // 3,145,728 B
  u16*   hT_b = (u16*)(w + 3145728);      // 3,145,728 B
  u16*   Abf  = (u16*)(w + 6291456);      // 25,165,824 B (4 layers)
  u16*   G    = (u16*)(w + 31457280);     // 9,437,184 B
  u16*   fswT = (u16*)(w + 40894464);     // 393,216 B
  u16*   WgT  = (u16*)(w + 41287680);     // 65,536 B
  u16*   g1wB = (u16*)(w + 41353216);     // 65,536 B
  u16*   gwB  = (u16*)(w + 41418752);     // 262,144 B
  u16*   owB  = (u16*)(w + 41680896);     // 8,192 B
  float* spb  = (float*)(w + 41689088);   // 1,048,576 B
  float* tpb  = (float*)(w + 42737664);   // 98,304 B
  float* ev   = (float*)(w + 42835968);   // 16,384 B
  u16*   ypt  = (u16*)(w + 42852352);     // 12,582,912 B (4 x 1,572,864 u16)
  u16*   catB = (u16*)(w + 55435264);     // 1,048,576 B
  u16*   sB   = (u16*)(w + 56483840);     // 1,048,576 B

  prep_kernel<<<4463, 256, 0, stream>>>(x, sape, tape, srpe, trpe, Wi, bi, gmu, gsg,
                                        Wg, bg, Wsp, Wtp, fsw, mask, g1w, gow, ow,
                                        hT_a, Abf, spb, tpb, fswT, WgT, ev,
                                        g1wB, gwB, owB);
  u16* hin = hT_a;
  u16* hout = hT_b;
  for (int l = 0; l < 4; ++l) {
    agg_kernel<<<288, 256, 0, stream>>>(Abf + (size_t)l * 3145728, hin, G);
    combine_kernel<<<192, 256, 0, stream>>>(G, ev + l * 144, WgT + l * 8192,
                                            spb + l * 65536, tpb + l * 6144,
                                            fswT + l * 49152, hout,
                                            ypt + (size_t)l * 1572864);
    u16* tmp = hin; hin = hout; hout = tmp;
  }
  glu1cat_kernel<<<64, 256, 0, stream>>>(ypt, fsb, g1wB, g1b, catB);
  gout_kernel<<<256, 256, 0, stream>>>(catB, gwB, gob, sB);
  head_kernel<<<32, 256, 0, stream>>>(sB, owB, obv, (float*)d_out);
}

// Round 16
// 242.316 us; speedup vs baseline: 1.0147x; 1.0147x over previous
//
#include <hip/hip_runtime.h>
#include <math.h>

// ---------------------------------------------------------------------------
// STPGCN forward. fp32 I/O, bf16 MFMA internal, fp32 accumulate.
// B=4 T=12 V=512 C=64 d=8 TS=3 P=12 L=4, BETA=2.
// R16 = R14 (champion: 237.6us, agg nt-slowest decode, ypt bf16) + ONE change
// from R15's bundle: t-reduce fused into glu1cat (kills reduce launch + 2MB
// yB round-trip). R15's 2D XCD swizzle (suspected regression: unverified
// bid%8->XCD mapping) NOT included. This attributes R15's +8us.
// Laws: cross-block sync costs more than a launch (R11/R13); no bundles.
// ---------------------------------------------------------------------------

typedef unsigned short u16;
typedef __attribute__((ext_vector_type(8))) short short8;
typedef __attribute__((ext_vector_type(4))) float f32x4;
typedef __attribute__((ext_vector_type(8))) unsigned short u16x8;
typedef __attribute__((ext_vector_type(4))) unsigned short u16x4;

#define MFMA16(a, b, c) __builtin_amdgcn_mfma_f32_16x16x32_bf16((a), (b), (c), 0, 0, 0)

__device__ __forceinline__ float b2f(u16 u) {
  union { unsigned int i; float f; } x; x.i = ((unsigned int)u) << 16; return x.f;
}
__device__ __forceinline__ u16 f2b(float f) {
  union { float f; unsigned int i; } x; x.f = f;
  unsigned int r = x.i + 0x7FFFu + ((x.i >> 16) & 1u);
  return (u16)(r >> 16);
}
__device__ __forceinline__ void ld8f(const float* __restrict__ p, float* f) {
  f32x4 a = *(const f32x4*)p;
  f32x4 b = *(const f32x4*)(p + 4);
  #pragma unroll
  for (int i = 0; i < 4; ++i) { f[i] = a[i]; f[4 + i] = b[i]; }
}
__device__ __forceinline__ float gcf(const float* e, const float* __restrict__ mu,
                                     const float* __restrict__ sg) {
  float s = 0.f;
  #pragma unroll
  for (int i = 0; i < 8; ++i) {
    float dm = e[i] - mu[i];
    s += dm * dm * sg[i] * sg[i];
  }
  return -0.5f * s;
}
__device__ __forceinline__ float sigm(float v) { return 1.0f / (1.0f + expf(-v)); }

// ---------------------------------------------------------------------------
// prep (R14-identical)
// ---------------------------------------------------------------------------
__global__ __launch_bounds__(256) void prep_kernel(
    const float* __restrict__ x, const float* __restrict__ sape,
    const float* __restrict__ tape, const float* __restrict__ srpe,
    const float* __restrict__ trpe, const float* __restrict__ Wi,
    const float* __restrict__ bi, const float* __restrict__ gmu,
    const float* __restrict__ gsg, const float* __restrict__ Wg,
    const float* __restrict__ bg, const float* __restrict__ Wsp,
    const float* __restrict__ Wtp, const float* __restrict__ fsw,
    const float* __restrict__ mask,
    const float* __restrict__ g1w, const float* __restrict__ gw,
    const float* __restrict__ ow,
    u16* __restrict__ hT0, u16* __restrict__ Abf,
    float* __restrict__ spb, float* __restrict__ tpb,
    u16* __restrict__ fswT, u16* __restrict__ WgT, float* __restrict__ ev,
    u16* __restrict__ g1wB, u16* __restrict__ gwB, u16* __restrict__ owB) {
  const int tid = threadIdx.x;
  int bid = blockIdx.x;

  if (bid < 768) {  // h0 -> hT0[b][t][c][i]
    int gid = bid * 256 + tid;                 // 196608 items
    int i8 = gid & 63, c = (gid >> 6) & 63, bt = gid >> 12;
    float xv[8];
    ld8f(&x[bt * 512 + i8 * 8], xv);
    float wic = Wi[c], bic = bi[c];
    u16x8 hv;
    #pragma unroll
    for (int ii = 0; ii < 8; ++ii) hv[ii] = f2b(xv[ii] * wic + bic);
    *(u16x8*)&hT0[gid * 8] = hv;
    return;
  }
  bid -= 768;
  if (bid < 1024) {  // Abf: thread per (j,i); expbase for 4 l's, then x mask
    int gid = bid * 256 + tid;                 // 262144
    int i = gid & 511, j = gid >> 9;
    float fi[8], fj[8], fr[8];
    ld8f(sape + i * 8, fi);
    ld8f(sape + j * 8, fj);
    ld8f(srpe + ((size_t)i * 512 + j) * 8, fr);
    u16 eb[4];
    #pragma unroll
    for (int l = 0; l < 4; ++l) {
      const float* mub = gmu + l * 48;
      const float* sgb = gsg + l * 48;
      float s = gcf(fi, mub + 0, sgb + 0)
              + gcf(fj, mub + 8, sgb + 8)
              + gcf(fr, mub + 32, sgb + 32);
      eb[l] = f2b(expf(s));
    }
    #pragma unroll
    for (int b = 0; b < 4; ++b)
      #pragma unroll
      for (int k = 0; k < 3; ++k) {
        float mv = mask[((size_t)(b * 512 + j)) * 1536 + k * 512 + i];
        u16 m = (mv != 0.f) ? (u16)0xFFFFu : (u16)0;
        #pragma unroll
        for (int l = 0; l < 4; ++l)
          Abf[((size_t)((l * 4 + b) * 512 + j)) * 1536 + k * 512 + i] = eb[l] & m;
      }
    return;
  }
  bid -= 1024;
  if (bid < 1024) {  // spb[l][j][o] = sape[j]·Wsp[l][:,o]
    int gid = bid * 256 + tid;                 // 262144
    int o = gid & 127, j = (gid >> 7) & 511, l = gid >> 16;
    float s = 0.f;
    #pragma unroll
    for (int dd = 0; dd < 8; ++dd)
      s += sape[j * 8 + dd] * Wsp[(l * 8 + dd) * 128 + o];
    spb[gid] = s;
    return;
  }
  bid -= 1024;
  if (bid < 96) {  // tpb[l][bt][o] = bg[l][o] + tape[bt]·Wtp[l][:,o]
    int gid = bid * 256 + tid;                 // 24576
    int o = gid & 127, bt = (gid >> 7) % 48, l = gid / 6144;
    float s = bg[l * 128 + o];
    #pragma unroll
    for (int dd = 0; dd < 8; ++dd)
      s += tape[bt * 8 + dd] * Wtp[(l * 8 + dd) * 128 + o];
    tpb[gid] = s;
    return;
  }
  bid -= 96;
  if (bid < 768) {  // fswT[l][o][t*64+c] = fs_w[l][o][c][t]
    int gid = bid * 256 + tid;                 // 196608
    int kidx = gid % 768, rest = gid / 768;
    int o = rest & 63, l = rest >> 6;
    int c = kidx & 63, tt = kidx >> 6;
    fswT[gid] = f2b(fsw[((l * 64 + o) * 64 + c) * 12 + tt]);
    return;
  }
  bid -= 768;
  if (bid < 128) {  // WgT[l][o][c] = Wg[l][c][o]
    int gid = bid * 256 + tid;                 // 32768
    int c = gid & 63, o = (gid >> 6) & 127, l = gid >> 13;
    WgT[gid] = f2b(Wg[(l * 64 + c) * 128 + o]);
    return;
  }
  bid -= 128;
  if (bid < 3) {  // ev[l][bt][k]
    int gid = bid * 256 + tid;
    if (gid < 576) {
      int k = gid % 3, t = (gid / 3) % 12, b = (gid / 36) % 4, l = gid / 144;
      const float* mub = gmu + l * 48;
      const float* sgb = gsg + l * 48;
      float e2[8], e3[8], e5[8];
      ld8f(tape + (b * 12 + t) * 8, e2);
      int tp = t + k - 2;
      if (tp >= 0) ld8f(tape + (b * 12 + tp) * 8, e3);
      else {
        #pragma unroll
        for (int ii = 0; ii < 8; ++ii) e3[ii] = 0.f;
      }
      ld8f(trpe + k * 8, e5);
      float s = gcf(e2, mub + 16, sgb + 16)
              + gcf(e3, mub + 24, sgb + 24)
              + gcf(e5, mub + 40, sgb + 40);
      ev[gid] = expf(s);
    }
    return;
  }
  bid -= 3;
  if (bid < 128) {  // g1wB
    int gid = bid * 256 + tid;
    g1wB[gid] = f2b(g1w[gid]);
    return;
  }
  bid -= 128;
  if (bid < 512) {  // gwB
    int gid = bid * 256 + tid;
    gwB[gid] = f2b(gw[gid]);
    return;
  }
  bid -= 512;
  {  // owB
    int gid = bid * 256 + tid;
    if (gid < 3072) owB[gid] = f2b(ow[gid]);
  }
}

// ---------------------------------------------------------------------------
// agg (R14-identical): nt slowest -> A-tile sharers 48 apart (XCD-local).
// ---------------------------------------------------------------------------
__global__ __launch_bounds__(256) void agg_kernel(
    const u16* __restrict__ Abfl, const u16* __restrict__ hT,
    u16* __restrict__ G) {
  __shared__ u16 As[128][72];
  __shared__ u16 Bs[128][72];
  const int tid = threadIdx.x, wid = tid >> 6, lane = tid & 63;
  const int l16 = lane & 15, quad = lane >> 4;
  const int bid = blockIdx.x;
  const int nt = bid / 48;          // slowest: XCD-local A reuse
  const int rest = bid % 48;
  const int mt = rest & 3;
  const int k  = (rest >> 2) % 3;
  const int b  = rest / 12;
  const int wm = wid >> 1, wn = wid & 1;

  const u16* Arow0 = Abfl + ((size_t)(b * 512 + mt * 128)) * 1536 + k * 512;
  f32x4 acc[4][4] = {};

  for (int it = 0; it < 8; ++it) {
    const int i0 = it * 64;
    #pragma unroll
    for (int s = 0; s < 4; ++s) {
      int idx = s * 256 + tid;
      int r = idx >> 3, ch = (idx & 7) * 8;
      *(u16x8*)&As[r][ch] = *(const u16x8*)&Arow0[(size_t)r * 1536 + i0 + ch];
      int tp = nt * 2 + (r >> 6), c = r & 63;
      *(u16x8*)&Bs[r][ch] =
          *(const u16x8*)&hT[((size_t)((b * 12 + tp) * 64 + c)) * 512 + i0 + ch];
    }
    __syncthreads();
    #pragma unroll
    for (int ks = 0; ks < 2; ++ks) {
      short8 af[4], bf[4];
      #pragma unroll
      for (int mb = 0; mb < 4; ++mb)
        af[mb] = *(const short8*)&As[wm * 64 + mb * 16 + l16][ks * 32 + quad * 8];
      #pragma unroll
      for (int nb = 0; nb < 4; ++nb)
        bf[nb] = *(const short8*)&Bs[wn * 64 + nb * 16 + l16][ks * 32 + quad * 8];
      #pragma unroll
      for (int mb = 0; mb < 4; ++mb)
        #pragma unroll
        for (int nb = 0; nb < 4; ++nb)
          acc[mb][nb] = MFMA16(af[mb], bf[nb], acc[mb][nb]);
    }
    __syncthreads();
  }

  // stage C (128x128 bf16 = 32KB) in LDS over As/Bs, then coalesced write
  u16* base = &As[0][0];
  #pragma unroll
  for (int mb = 0; mb < 4; ++mb)
    #pragma unroll
    for (int nb = 0; nb < 4; ++nb) {
      int n = wn * 64 + nb * 16 + l16;
      #pragma unroll
      for (int r = 0; r < 4; ++r) {
        int m = wm * 64 + mb * 16 + quad * 4 + r;
        base[m * 128 + n] = f2b(acc[mb][nb][r]);
      }
    }
  __syncthreads();
  u16* Gp = G + ((size_t)((b * 3 + k) * 512 + mt * 128)) * 768 + nt * 128;
  #pragma unroll
  for (int s = 0; s < 8; ++s) {
    int idx = s * 256 + tid;
    int m = idx >> 4, ch = (idx & 15) * 8;
    *(u16x8*)&Gp[(size_t)m * 768 + ch] = *(const u16x8*)&base[m * 128 + ch];
  }
}

// ---------------------------------------------------------------------------
// combine (R14-identical; ypt bf16)
// ---------------------------------------------------------------------------
__global__ __launch_bounds__(256) void combine_kernel(
    const u16* __restrict__ G, const float* __restrict__ evl,
    const u16* __restrict__ WgTl, const float* __restrict__ spbl,
    const float* __restrict__ tpbl, const u16* __restrict__ fswTl,
    u16* __restrict__ hTout, u16* __restrict__ yptl) {
  __shared__ u16 aggL[128][72];
  __shared__ u16 hL[128][72];
  const int tid = threadIdx.x, wid = tid >> 6, lane = tid & 63;
  const int l16 = lane & 15, quad = lane >> 4;
  const int bid = blockIdx.x;
  const int mt = bid & 3;
  const int bt = bid >> 2;
  const int b = bt / 12, t = bt - b * 12;

  {  // combine G over k (fp32), thread = (j, 32-c half)
    int j = tid >> 1;
    int c0 = (tid & 1) * 32;
    float accv[32];
    #pragma unroll
    for (int ii = 0; ii < 32; ++ii) accv[ii] = 0.f;
    #pragma unroll
    for (int k = 0; k < 3; ++k) {
      int tp = t + k - 2;
      if (tp < 0) continue;
      float ek = evl[bt * 3 + k];
      const u16* gp = &G[((size_t)((b * 3 + k) * 512 + mt * 128 + j)) * 768 + tp * 64 + c0];
      #pragma unroll
      for (int s = 0; s < 4; ++s) {
        u16x8 gv = *(const u16x8*)&gp[s * 8];
        #pragma unroll
        for (int ii = 0; ii < 8; ++ii) accv[s * 8 + ii] += b2f(gv[ii]) * ek;
      }
    }
    #pragma unroll
    for (int s = 0; s < 4; ++s) {
      u16x8 ov;
      #pragma unroll
      for (int ii = 0; ii < 8; ++ii) ov[ii] = f2b(accv[s * 8 + ii]);
      *(u16x8*)&aggL[j][c0 + s * 8] = ov;
    }
  }
  __syncthreads();

  // phase 2: g[o,j] = sum_c WgT[o][c]*agg[j][c]
  f32x4 acc2[8][2] = {};
  #pragma unroll
  for (int ks = 0; ks < 2; ++ks) {
    short8 bf[2];
    #pragma unroll
    for (int nb = 0; nb < 2; ++nb)
      bf[nb] = *(const short8*)&aggL[wid * 32 + nb * 16 + l16][ks * 32 + quad * 8];
    #pragma unroll
    for (int mb = 0; mb < 8; ++mb) {
      short8 a = *(const short8*)&WgTl[(mb * 16 + l16) * 64 + ks * 32 + quad * 8];
      acc2[mb][0] = MFMA16(a, bf[0], acc2[mb][0]);
      acc2[mb][1] = MFMA16(a, bf[1], acc2[mb][1]);
    }
  }

  // epilogue: + spb + tpb, GLU, write hTout + hL
  #pragma unroll
  for (int mb = 0; mb < 4; ++mb) {
    int ob = mb * 16 + quad * 4;
    #pragma unroll
    for (int nb = 0; nb < 2; ++nb) {
      int jl = wid * 32 + nb * 16 + l16;
      int jg = mt * 128 + jl;
      f32x4 spl = *(const f32x4*)&spbl[jg * 128 + ob];
      f32x4 spr = *(const f32x4*)&spbl[jg * 128 + 64 + ob];
      f32x4 tpl = *(const f32x4*)&tpbl[bt * 128 + ob];
      f32x4 tpr = *(const f32x4*)&tpbl[bt * 128 + 64 + ob];
      #pragma unroll
      for (int r = 0; r < 4; ++r) {
        float vl = acc2[mb][nb][r] + spl[r] + tpl[r];
        float vr = acc2[mb + 4][nb][r] + spr[r] + tpr[r];
        u16 hb = f2b(vl * sigm(vr));
        hTout[((size_t)((b * 12 + t) * 64 + ob + r)) * 512 + jg] = hb;
        hL[jl][ob + r] = hb;
      }
    }
  }
  __syncthreads();

  // GFS partial: y_t[o][j] = sum_c fswT[o][t*64+c] * h[j][c] -> ypt bf16
  f32x4 accY[4][2] = {};
  #pragma unroll
  for (int ks = 0; ks < 2; ++ks) {
    short8 bfv[2];
    #pragma unroll
    for (int nb = 0; nb < 2; ++nb)
      bfv[nb] = *(const short8*)&hL[wid * 32 + nb * 16 + l16][ks * 32 + quad * 8];
    #pragma unroll
    for (int mb = 0; mb < 4; ++mb) {
      short8 a = *(const short8*)&fswTl[(mb * 16 + l16) * 768 + t * 64 + ks * 32 + quad * 8];
      accY[mb][0] = MFMA16(a, bfv[0], accY[mb][0]);
      accY[mb][1] = MFMA16(a, bfv[1], accY[mb][1]);
    }
  }
  #pragma unroll
  for (int mb = 0; mb < 4; ++mb)
    #pragma unroll
    for (int nb = 0; nb < 2; ++nb) {
      int j = mt * 128 + wid * 32 + nb * 16 + l16;
      #pragma unroll
      for (int r = 0; r < 4; ++r) {
        int o = mb * 16 + quad * 4 + r;
        yptl[((size_t)(bt * 64 + o)) * 512 + j] = f2b(accY[mb][nb][r]);
      }
    }
}

// ---------------------------------------------------------------------------
// glu1cat + fused t-reduce (the ONE change vs R14): yL[v][o] = sum_t ypt +
// fsb in fp32 (same order as R14's reduce -> same rounding), then GLU1 GEMM
// -> catB. grid 64.
// ---------------------------------------------------------------------------
__global__ __launch_bounds__(256) void glu1cat_kernel(
    const u16* __restrict__ ypt, const float* __restrict__ fsb,
    const u16* __restrict__ g1wB, const float* __restrict__ g1b,
    u16* __restrict__ catB) {
  __shared__ u16 yL[128][72];
  const int tid = threadIdx.x, wid = tid >> 6, lane = tid & 63;
  const int l16 = lane & 15, quad = lane >> 4;
  const int l = blockIdx.x >> 4;
  const int b = (blockIdx.x >> 2) & 3;
  const int v0 = (blockIdx.x & 3) * 128;

  {  // t-reduce: thread = (o, 32-v group)
    int o = tid & 63, sv = tid >> 6;
    float accv[32];
    float fb = fsb[l * 64 + o];
    #pragma unroll
    for (int ii = 0; ii < 32; ++ii) accv[ii] = fb;
    for (int t = 0; t < 12; ++t) {
      const u16* src = &ypt[(size_t)l * 1572864 +
                            ((size_t)((b * 12 + t) * 64 + o)) * 512 + v0 + sv * 32];
      #pragma unroll
      for (int s = 0; s < 4; ++s) {
        u16x8 v = *(const u16x8*)&src[s * 8];
        #pragma unroll
        for (int ii = 0; ii < 8; ++ii) accv[s * 8 + ii] += b2f(v[ii]);
      }
    }
    #pragma unroll
    for (int ii = 0; ii < 32; ++ii) yL[sv * 32 + ii][o] = f2b(accv[ii]);
  }
  __syncthreads();

  f32x4 acc[2][8] = {};
  #pragma unroll
  for (int ks = 0; ks < 2; ++ks) {
    short8 a0 = *(const short8*)&g1wB[l * 8192 + (wid * 16 + l16) * 64 +
                                      ks * 32 + quad * 8];
    short8 a1 = *(const short8*)&g1wB[l * 8192 + (64 + wid * 16 + l16) * 64 +
                                      ks * 32 + quad * 8];
    #pragma unroll
    for (int nb = 0; nb < 8; ++nb) {
      short8 bf = *(const short8*)&yL[nb * 16 + l16][ks * 32 + quad * 8];
      acc[0][nb] = MFMA16(a0, bf, acc[0][nb]);
      acc[1][nb] = MFMA16(a1, bf, acc[1][nb]);
    }
  }
  #pragma unroll
  for (int nb = 0; nb < 8; ++nb) {
    int v = v0 + nb * 16 + l16;
    int oc = wid * 16 + quad * 4;
    u16x4 pk;
    #pragma unroll
    for (int r = 0; r < 4; ++r) {
      float zl = acc[0][nb][r] + g1b[l * 128 + oc + r];
      float zr = acc[1][nb][r] + g1b[l * 128 + 64 + oc + r];
      pk[r] = f2b(zl * sigm(zr));
    }
    *(u16x4*)&catB[((size_t)(b * 512 + v)) * 256 + l * 64 + oc] = pk;
  }
}

// ---------------------------------------------------------------------------
// gout (R14-identical)
// ---------------------------------------------------------------------------
__global__ __launch_bounds__(256) void gout_kernel(
    const u16* __restrict__ catB, const u16* __restrict__ gwB,
    const float* __restrict__ gb, u16* __restrict__ sB) {
  __shared__ u16 cL[64][264];
  const int tid = threadIdx.x, wid = tid >> 6, lane = tid & 63;
  const int l16 = lane & 15, quad = lane >> 4;
  const int wm = wid >> 1, wn = wid & 1;
  const int b = blockIdx.x >> 6;
  const int v0 = ((blockIdx.x >> 3) & 7) * 64;
  const int cc0 = (blockIdx.x & 7) * 32;

  {
    int v = tid >> 2, seg = (tid & 3) * 64;
    const u16* src = &catB[((size_t)(b * 512 + v0 + v)) * 256 + seg];
    #pragma unroll
    for (int s = 0; s < 8; ++s)
      *(u16x8*)&cL[v][seg + s * 8] = *(const u16x8*)&src[s * 8];
  }
  __syncthreads();

  f32x4 acc[2][2] = {};
  #pragma unroll
  for (int ks = 0; ks < 8; ++ks) {
    short8 aL = *(const short8*)&gwB[(cc0 + wm * 16 + l16) * 256 +
                                     ks * 32 + quad * 8];
    short8 aH = *(const short8*)&gwB[(256 + cc0 + wm * 16 + l16) * 256 +
                                     ks * 32 + quad * 8];
    #pragma unroll
    for (int nb = 0; nb < 2; ++nb) {
      short8 bf = *(const short8*)&cL[wn * 32 + nb * 16 + l16][ks * 32 + quad * 8];
      acc[0][nb] = MFMA16(aL, bf, acc[0][nb]);
      acc[1][nb] = MFMA16(aH, bf, acc[1][nb]);
    }
  }
  #pragma unroll
  for (int nb = 0; nb < 2; ++nb) {
    int v = v0 + wn * 32 + nb * 16 + l16;
    int cc = cc0 + wm * 16 + quad * 4;
    u16x4 pk;
    #pragma unroll
    for (int r = 0; r < 4; ++r) {
      float zl = acc[0][nb][r] + gb[cc + r];
      float zr = acc[1][nb][r] + gb[256 + cc + r];
      pk[r] = f2b(zl * sigm(zr));
    }
    *(u16x4*)&sB[((size_t)(b * 512 + v)) * 256 + cc] = pk;
  }
}

// ---------------------------------------------------------------------------
// head (R14-identical)
// ---------------------------------------------------------------------------
__global__ __launch_bounds__(256) void head_kernel(
    const u16* __restrict__ sB, const u16* __restrict__ owB,
    const float* __restrict__ obv, float* __restrict__ out) {
  const int tid = threadIdx.x, wid = tid >> 6, lane = tid & 63;
  const int l16 = lane & 15, quad = lane >> 4;
  const int b = blockIdx.x >> 3;
  const int v0 = (blockIdx.x & 7) * 64;

  f32x4 acc = {};
  #pragma unroll
  for (int ks = 0; ks < 8; ++ks) {
    short8 a;
    if (l16 < 12) a = *(const short8*)&owB[l16 * 256 + ks * 32 + quad * 8];
    else {
      #pragma unroll
      for (int ii = 0; ii < 8; ++ii) a[ii] = 0;
    }
    short8 bf = *(const short8*)&sB[((size_t)(b * 512 + v0 + wid * 16 + l16)) * 256 +
                                    ks * 32 + quad * 8];
    acc = MFMA16(a, bf, acc);
  }
  #pragma unroll
  for (int r = 0; r < 4; ++r) {
    int p = quad * 4 + r;
    if (p < 12)
      out[(b * 12 + p) * 512 + v0 + wid * 16 + l16] = acc[r] + obv[p];
  }
}

// ---------------------------------------------------------------------------
extern "C" void kernel_launch(void* const* d_in, const int* in_sizes, int n_in,
                              void* d_out, int out_size, void* d_ws, size_t ws_size,
                              hipStream_t stream) {
  const float* x    = (const float*)d_in[0];
  const float* sape = (const float*)d_in[1];
  const float* tape = (const float*)d_in[2];
  const float* srpe = (const float*)d_in[3];
  const float* trpe = (const float*)d_in[4];
  const float* mask = (const float*)d_in[7];
  const float* Wi   = (const float*)d_in[8];
  const float* bi   = (const float*)d_in[9];
  const float* gmu  = (const float*)d_in[10];
  const float* gsg  = (const float*)d_in[11];
  const float* Wg   = (const float*)d_in[12];
  const float* bg   = (const float*)d_in[13];
  const float* Wsp  = (const float*)d_in[14];
  const float* Wtp  = (const float*)d_in[15];
  const float* fsw  = (const float*)d_in[16];
  const float* fsb  = (const float*)d_in[17];
  const float* g1w  = (const float*)d_in[18];
  const float* g1b  = (const float*)d_in[19];
  const float* gow  = (const float*)d_in[20];
  const float* gob  = (const float*)d_in[21];
  const float* ow   = (const float*)d_in[22];
  const float* obv  = (const float*)d_in[23];

  char* w = (char*)d_ws;
  u16*   hT_a = (u16*)(w + 0);            // 3,145,728 B
  u16*   hT_b = (u16*)(w + 3145728);      // 3,145,728 B
  u16*   Abf  = (u16*)(w + 6291456);      // 25,165,824 B (4 layers)
  u16*   G    = (u16*)(w + 31457280);     // 9,437,184 B
  u16*   fswT = (u16*)(w + 40894464);     // 393,216 B
  u16*   WgT  = (u16*)(w + 41287680);     // 65,536 B
  u16*   g1wB = (u16*)(w + 41353216);     // 65,536 B
  u16*   gwB  = (u16*)(w + 41418752);     // 262,144 B
  u16*   owB  = (u16*)(w + 41680896);     // 8,192 B
  float* spb  = (float*)(w + 41689088);   // 1,048,576 B
  float* tpb  = (float*)(w + 42737664);   // 98,304 B
  float* ev   = (float*)(w + 42835968);   // 16,384 B
  u16*   ypt  = (u16*)(w + 42852352);     // 12,582,912 B (4 x 1,572,864 u16)
  u16*   catB = (u16*)(w + 55435264);     // 1,048,576 B
  u16*   sB   = (u16*)(w + 56483840);     // 1,048,576 B

  prep_kernel<<<4463, 256, 0, stream>>>(x, sape, tape, srpe, trpe, Wi, bi, gmu, gsg,
                                        Wg, bg, Wsp, Wtp, fsw, mask, g1w, gow, ow,
                                        hT_a, Abf, spb, tpb, fswT, WgT, ev,
                                        g1wB, gwB, owB);
  u16* hin = hT_a;
  u16* hout = hT_b;
  for (int l = 0; l < 4; ++l) {
    agg_kernel<<<288, 256, 0, stream>>>(Abf + (size_t)l * 3145728, hin, G);
    combine_kernel<<<192, 256, 0, stream>>>(G, ev + l * 144, WgT + l * 8192,
                                            spb + l * 65536, tpb + l * 6144,
                                            fswT + l * 49152, hout,
                                            ypt + (size_t)l * 1572864);
    u16* tmp = hin; hin = hout; hout = tmp;
  }
  glu1cat_kernel<<<64, 256, 0, stream>>>(ypt, fsb, g1wB, g1b, catB);
  gout_kernel<<<256, 256, 0, stream>>>(catB, gwB, gob, sB);
  head_kernel<<<32, 256, 0, stream>>>(sB, owB, obv, (float*)d_out);
}

// Round 17
// 236.539 us; speedup vs baseline: 1.0394x; 1.0244x over previous
//
#include <hip/hip_runtime.h>
#include <math.h>

// ---------------------------------------------------------------------------
// STPGCN forward. fp32 I/O, bf16 MFMA internal, fp32 accumulate.
// B=4 T=12 V=512 C=64 d=8 TS=3 P=12 L=4, BETA=2.
// R17 = R14 verbatim (champion: 237.6us). Attribution complete:
//  R15 = R14 + xcd-swizzle + fused-reduce = 245.9 (+8.3)
//  R16 = R14 + fused-reduce             = 242.3 (+4.7)  => swizzle +3.6
// Both reverted. Laws learned across R5..R16: (1) cross-block sync
// (fence/atomic/grid-barrier) costs more than a launch boundary on CDNA4
// (R11 446us, R13 401us); (2) phases must stay wide (R7/R15b); (3) one
// change per round or attribution is lost (R5/R12/R15).
// ---------------------------------------------------------------------------

typedef unsigned short u16;
typedef __attribute__((ext_vector_type(8))) short short8;
typedef __attribute__((ext_vector_type(4))) float f32x4;
typedef __attribute__((ext_vector_type(8))) unsigned short u16x8;
typedef __attribute__((ext_vector_type(4))) unsigned short u16x4;

#define MFMA16(a, b, c) __builtin_amdgcn_mfma_f32_16x16x32_bf16((a), (b), (c), 0, 0, 0)

__device__ __forceinline__ float b2f(u16 u) {
  union { unsigned int i; float f; } x; x.i = ((unsigned int)u) << 16; return x.f;
}
__device__ __forceinline__ u16 f2b(float f) {
  union { float f; unsigned int i; } x; x.f = f;
  unsigned int r = x.i + 0x7FFFu + ((x.i >> 16) & 1u);
  return (u16)(r >> 16);
}
__device__ __forceinline__ void ld8f(const float* __restrict__ p, float* f) {
  f32x4 a = *(const f32x4*)p;
  f32x4 b = *(const f32x4*)(p + 4);
  #pragma unroll
  for (int i = 0; i < 4; ++i) { f[i] = a[i]; f[4 + i] = b[i]; }
}
__device__ __forceinline__ float gcf(const float* e, const float* __restrict__ mu,
                                     const float* __restrict__ sg) {
  float s = 0.f;
  #pragma unroll
  for (int i = 0; i < 8; ++i) {
    float dm = e[i] - mu[i];
    s += dm * dm * sg[i] * sg[i];
  }
  return -0.5f * s;
}
__device__ __forceinline__ float sigm(float v) { return 1.0f / (1.0f + expf(-v)); }

// ---------------------------------------------------------------------------
// prep
// ---------------------------------------------------------------------------
__global__ __launch_bounds__(256) void prep_kernel(
    const float* __restrict__ x, const float* __restrict__ sape,
    const float* __restrict__ tape, const float* __restrict__ srpe,
    const float* __restrict__ trpe, const float* __restrict__ Wi,
    const float* __restrict__ bi, const float* __restrict__ gmu,
    const float* __restrict__ gsg, const float* __restrict__ Wg,
    const float* __restrict__ bg, const float* __restrict__ Wsp,
    const float* __restrict__ Wtp, const float* __restrict__ fsw,
    const float* __restrict__ mask,
    const float* __restrict__ g1w, const float* __restrict__ gw,
    const float* __restrict__ ow,
    u16* __restrict__ hT0, u16* __restrict__ Abf,
    float* __restrict__ spb, float* __restrict__ tpb,
    u16* __restrict__ fswT, u16* __restrict__ WgT, float* __restrict__ ev,
    u16* __restrict__ g1wB, u16* __restrict__ gwB, u16* __restrict__ owB) {
  const int tid = threadIdx.x;
  int bid = blockIdx.x;

  if (bid < 768) {  // h0 -> hT0[b][t][c][i]
    int gid = bid * 256 + tid;                 // 196608 items
    int i8 = gid & 63, c = (gid >> 6) & 63, bt = gid >> 12;
    float xv[8];
    ld8f(&x[bt * 512 + i8 * 8], xv);
    float wic = Wi[c], bic = bi[c];
    u16x8 hv;
    #pragma unroll
    for (int ii = 0; ii < 8; ++ii) hv[ii] = f2b(xv[ii] * wic + bic);
    *(u16x8*)&hT0[gid * 8] = hv;
    return;
  }
  bid -= 768;
  if (bid < 1024) {  // Abf: thread per (j,i); expbase for 4 l's, then x mask
    int gid = bid * 256 + tid;                 // 262144
    int i = gid & 511, j = gid >> 9;
    float fi[8], fj[8], fr[8];
    ld8f(sape + i * 8, fi);
    ld8f(sape + j * 8, fj);
    ld8f(srpe + ((size_t)i * 512 + j) * 8, fr);
    u16 eb[4];
    #pragma unroll
    for (int l = 0; l < 4; ++l) {
      const float* mub = gmu + l * 48;
      const float* sgb = gsg + l * 48;
      float s = gcf(fi, mub + 0, sgb + 0)
              + gcf(fj, mub + 8, sgb + 8)
              + gcf(fr, mub + 32, sgb + 32);
      eb[l] = f2b(expf(s));
    }
    #pragma unroll
    for (int b = 0; b < 4; ++b)
      #pragma unroll
      for (int k = 0; k < 3; ++k) {
        float mv = mask[((size_t)(b * 512 + j)) * 1536 + k * 512 + i];
        u16 m = (mv != 0.f) ? (u16)0xFFFFu : (u16)0;
        #pragma unroll
        for (int l = 0; l < 4; ++l)
          Abf[((size_t)((l * 4 + b) * 512 + j)) * 1536 + k * 512 + i] = eb[l] & m;
      }
    return;
  }
  bid -= 1024;
  if (bid < 1024) {  // spb[l][j][o] = sape[j]·Wsp[l][:,o]
    int gid = bid * 256 + tid;                 // 262144
    int o = gid & 127, j = (gid >> 7) & 511, l = gid >> 16;
    float s = 0.f;
    #pragma unroll
    for (int dd = 0; dd < 8; ++dd)
      s += sape[j * 8 + dd] * Wsp[(l * 8 + dd) * 128 + o];
    spb[gid] = s;
    return;
  }
  bid -= 1024;
  if (bid < 96) {  // tpb[l][bt][o] = bg[l][o] + tape[bt]·Wtp[l][:,o]
    int gid = bid * 256 + tid;                 // 24576
    int o = gid & 127, bt = (gid >> 7) % 48, l = gid / 6144;
    float s = bg[l * 128 + o];
    #pragma unroll
    for (int dd = 0; dd < 8; ++dd)
      s += tape[bt * 8 + dd] * Wtp[(l * 8 + dd) * 128 + o];
    tpb[gid] = s;
    return;
  }
  bid -= 96;
  if (bid < 768) {  // fswT[l][o][t*64+c] = fs_w[l][o][c][t]
    int gid = bid * 256 + tid;                 // 196608
    int kidx = gid % 768, rest = gid / 768;
    int o = rest & 63, l = rest >> 6;
    int c = kidx & 63, tt = kidx >> 6;
    fswT[gid] = f2b(fsw[((l * 64 + o) * 64 + c) * 12 + tt]);
    return;
  }
  bid -= 768;
  if (bid < 128) {  // WgT[l][o][c] = Wg[l][c][o]
    int gid = bid * 256 + tid;                 // 32768
    int c = gid & 63, o = (gid >> 6) & 127, l = gid >> 13;
    WgT[gid] = f2b(Wg[(l * 64 + c) * 128 + o]);
    return;
  }
  bid -= 128;
  if (bid < 3) {  // ev[l][bt][k]
    int gid = bid * 256 + tid;
    if (gid < 576) {
      int k = gid % 3, t = (gid / 3) % 12, b = (gid / 36) % 4, l = gid / 144;
      const float* mub = gmu + l * 48;
      const float* sgb = gsg + l * 48;
      float e2[8], e3[8], e5[8];
      ld8f(tape + (b * 12 + t) * 8, e2);
      int tp = t + k - 2;
      if (tp >= 0) ld8f(tape + (b * 12 + tp) * 8, e3);
      else {
        #pragma unroll
        for (int ii = 0; ii < 8; ++ii) e3[ii] = 0.f;
      }
      ld8f(trpe + k * 8, e5);
      float s = gcf(e2, mub + 16, sgb + 16)
              + gcf(e3, mub + 24, sgb + 24)
              + gcf(e5, mub + 40, sgb + 40);
      ev[gid] = expf(s);
    }
    return;
  }
  bid -= 3;
  if (bid < 128) {  // g1wB
    int gid = bid * 256 + tid;
    g1wB[gid] = f2b(g1w[gid]);
    return;
  }
  bid -= 128;
  if (bid < 512) {  // gwB
    int gid = bid * 256 + tid;
    gwB[gid] = f2b(gw[gid]);
    return;
  }
  bid -= 512;
  {  // owB
    int gid = bid * 256 + tid;
    if (gid < 3072) owB[gid] = f2b(ow[gid]);
  }
}

// ---------------------------------------------------------------------------
// agg: G[b,k,j,t'*64+c] = sum_i Abf_l[b,j,k*512+i]*hT[b,t',c,i]
// grid 288. nt slowest -> the 6 blocks sharing an A-tile are 48 apart
// (same XCD L2). C tile staged in LDS -> coalesced 16B/lane G stores.
// ---------------------------------------------------------------------------
__global__ __launch_bounds__(256) void agg_kernel(
    const u16* __restrict__ Abfl, const u16* __restrict__ hT,
    u16* __restrict__ G) {
  __shared__ u16 As[128][72];
  __shared__ u16 Bs[128][72];
  const int tid = threadIdx.x, wid = tid >> 6, lane = tid & 63;
  const int l16 = lane & 15, quad = lane >> 4;
  const int bid = blockIdx.x;
  const int nt = bid / 48;          // slowest: XCD-local A reuse
  const int rest = bid % 48;
  const int mt = rest & 3;
  const int k  = (rest >> 2) % 3;
  const int b  = rest / 12;
  const int wm = wid >> 1, wn = wid & 1;

  const u16* Arow0 = Abfl + ((size_t)(b * 512 + mt * 128)) * 1536 + k * 512;
  f32x4 acc[4][4] = {};

  for (int it = 0; it < 8; ++it) {
    const int i0 = it * 64;
    #pragma unroll
    for (int s = 0; s < 4; ++s) {
      int idx = s * 256 + tid;
      int r = idx >> 3, ch = (idx & 7) * 8;
      *(u16x8*)&As[r][ch] = *(const u16x8*)&Arow0[(size_t)r * 1536 + i0 + ch];
      int tp = nt * 2 + (r >> 6), c = r & 63;
      *(u16x8*)&Bs[r][ch] =
          *(const u16x8*)&hT[((size_t)((b * 12 + tp) * 64 + c)) * 512 + i0 + ch];
    }
    __syncthreads();
    #pragma unroll
    for (int ks = 0; ks < 2; ++ks) {
      short8 af[4], bf[4];
      #pragma unroll
      for (int mb = 0; mb < 4; ++mb)
        af[mb] = *(const short8*)&As[wm * 64 + mb * 16 + l16][ks * 32 + quad * 8];
      #pragma unroll
      for (int nb = 0; nb < 4; ++nb)
        bf[nb] = *(const short8*)&Bs[wn * 64 + nb * 16 + l16][ks * 32 + quad * 8];
      #pragma unroll
      for (int mb = 0; mb < 4; ++mb)
        #pragma unroll
        for (int nb = 0; nb < 4; ++nb)
          acc[mb][nb] = MFMA16(af[mb], bf[nb], acc[mb][nb]);
    }
    __syncthreads();
  }

  // stage C (128x128 bf16 = 32KB) in LDS over As/Bs, then coalesced write
  u16* base = &As[0][0];
  #pragma unroll
  for (int mb = 0; mb < 4; ++mb)
    #pragma unroll
    for (int nb = 0; nb < 4; ++nb) {
      int n = wn * 64 + nb * 16 + l16;
      #pragma unroll
      for (int r = 0; r < 4; ++r) {
        int m = wm * 64 + mb * 16 + quad * 4 + r;
        base[m * 128 + n] = f2b(acc[mb][nb][r]);
      }
    }
  __syncthreads();
  u16* Gp = G + ((size_t)((b * 3 + k) * 512 + mt * 128)) * 768 + nt * 128;
  #pragma unroll
  for (int s = 0; s < 8; ++s) {
    int idx = s * 256 + tid;
    int m = idx >> 4, ch = (idx & 15) * 8;
    *(u16x8*)&Gp[(size_t)m * 768 + ch] = *(const u16x8*)&base[m * 128 + ch];
  }
}

// ---------------------------------------------------------------------------
// combine: C=sum_k e_k*G -> xWgT + spb/tpb + GLU -> hTout; per-t GFS
// partial -> ypt bf16. grid 192 = (b,t) x mt(4).
// ---------------------------------------------------------------------------
__global__ __launch_bounds__(256) void combine_kernel(
    const u16* __restrict__ G, const float* __restrict__ evl,
    const u16* __restrict__ WgTl, const float* __restrict__ spbl,
    const float* __restrict__ tpbl, const u16* __restrict__ fswTl,
    u16* __restrict__ hTout, u16* __restrict__ yptl) {
  __shared__ u16 aggL[128][72];
  __shared__ u16 hL[128][72];
  const int tid = threadIdx.x, wid = tid >> 6, lane = tid & 63;
  const int l16 = lane & 15, quad = lane >> 4;
  const int bid = blockIdx.x;
  const int mt = bid & 3;
  const int bt = bid >> 2;
  const int b = bt / 12, t = bt - b * 12;

  {  // combine G over k (fp32), thread = (j, 32-c half)
    int j = tid >> 1;
    int c0 = (tid & 1) * 32;
    float accv[32];
    #pragma unroll
    for (int ii = 0; ii < 32; ++ii) accv[ii] = 0.f;
    #pragma unroll
    for (int k = 0; k < 3; ++k) {
      int tp = t + k - 2;
      if (tp < 0) continue;
      float ek = evl[bt * 3 + k];
      const u16* gp = &G[((size_t)((b * 3 + k) * 512 + mt * 128 + j)) * 768 + tp * 64 + c0];
      #pragma unroll
      for (int s = 0; s < 4; ++s) {
        u16x8 gv = *(const u16x8*)&gp[s * 8];
        #pragma unroll
        for (int ii = 0; ii < 8; ++ii) accv[s * 8 + ii] += b2f(gv[ii]) * ek;
      }
    }
    #pragma unroll
    for (int s = 0; s < 4; ++s) {
      u16x8 ov;
      #pragma unroll
      for (int ii = 0; ii < 8; ++ii) ov[ii] = f2b(accv[s * 8 + ii]);
      *(u16x8*)&aggL[j][c0 + s * 8] = ov;
    }
  }
  __syncthreads();

  // phase 2: g[o,j] = sum_c WgT[o][c]*agg[j][c]
  f32x4 acc2[8][2] = {};
  #pragma unroll
  for (int ks = 0; ks < 2; ++ks) {
    short8 bf[2];
    #pragma unroll
    for (int nb = 0; nb < 2; ++nb)
      bf[nb] = *(const short8*)&aggL[wid * 32 + nb * 16 + l16][ks * 32 + quad * 8];
    #pragma unroll
    for (int mb = 0; mb < 8; ++mb) {
      short8 a = *(const short8*)&WgTl[(mb * 16 + l16) * 64 + ks * 32 + quad * 8];
      acc2[mb][0] = MFMA16(a, bf[0], acc2[mb][0]);
      acc2[mb][1] = MFMA16(a, bf[1], acc2[mb][1]);
    }
  }

  // epilogue: + spb + tpb, GLU, write hTout + hL
  #pragma unroll
  for (int mb = 0; mb < 4; ++mb) {
    int ob = mb * 16 + quad * 4;
    #pragma unroll
    for (int nb = 0; nb < 2; ++nb) {
      int jl = wid * 32 + nb * 16 + l16;
      int jg = mt * 128 + jl;
      f32x4 spl = *(const f32x4*)&spbl[jg * 128 + ob];
      f32x4 spr = *(const f32x4*)&spbl[jg * 128 + 64 + ob];
      f32x4 tpl = *(const f32x4*)&tpbl[bt * 128 + ob];
      f32x4 tpr = *(const f32x4*)&tpbl[bt * 128 + 64 + ob];
      #pragma unroll
      for (int r = 0; r < 4; ++r) {
        float vl = acc2[mb][nb][r] + spl[r] + tpl[r];
        float vr = acc2[mb + 4][nb][r] + spr[r] + tpr[r];
        u16 hb = f2b(vl * sigm(vr));
        hTout[((size_t)((b * 12 + t) * 64 + ob + r)) * 512 + jg] = hb;
        hL[jl][ob + r] = hb;
      }
    }
  }
  __syncthreads();

  // GFS partial: y_t[o][j] = sum_c fswT[o][t*64+c] * h[j][c] -> ypt bf16
  f32x4 accY[4][2] = {};
  #pragma unroll
  for (int ks = 0; ks < 2; ++ks) {
    short8 bfv[2];
    #pragma unroll
    for (int nb = 0; nb < 2; ++nb)
      bfv[nb] = *(const short8*)&hL[wid * 32 + nb * 16 + l16][ks * 32 + quad * 8];
    #pragma unroll
    for (int mb = 0; mb < 4; ++mb) {
      short8 a = *(const short8*)&fswTl[(mb * 16 + l16) * 768 + t * 64 + ks * 32 + quad * 8];
      accY[mb][0] = MFMA16(a, bfv[0], accY[mb][0]);
      accY[mb][1] = MFMA16(a, bfv[1], accY[mb][1]);
    }
  }
  #pragma unroll
  for (int mb = 0; mb < 4; ++mb)
    #pragma unroll
    for (int nb = 0; nb < 2; ++nb) {
      int j = mt * 128 + wid * 32 + nb * 16 + l16;
      #pragma unroll
      for (int r = 0; r < 4; ++r) {
        int o = mb * 16 + quad * 4 + r;
        yptl[((size_t)(bt * 64 + o)) * 512 + j] = f2b(accY[mb][nb][r]);
      }
    }
}

// ---------------------------------------------------------------------------
// reduce: yB[l][b][o][v] = bf16(sum_t ypt(bf16) + fsb). grid 512.
// ---------------------------------------------------------------------------
__global__ __launch_bounds__(256) void reduce_kernel(
    const u16* __restrict__ ypt, const float* __restrict__ fsb,
    u16* __restrict__ yB) {
  int gid = blockIdx.x * 256 + threadIdx.x;    // 131072
  int j4 = gid & 127, o = (gid >> 7) & 63, b = (gid >> 13) & 3, l = gid >> 15;
  const u16* base = &ypt[(size_t)l * 1572864 +
                         ((size_t)((b * 12) * 64 + o)) * 512 + j4 * 4];
  float fb = fsb[l * 64 + o];
  f32x4 s = {fb, fb, fb, fb};
  #pragma unroll
  for (int t = 0; t < 12; ++t) {
    u16x4 v = *(const u16x4*)&base[(size_t)t * 32768];
    #pragma unroll
    for (int ii = 0; ii < 4; ++ii) s[ii] += b2f(v[ii]);
  }
  u16x4 pk;
  #pragma unroll
  for (int ii = 0; ii < 4; ++ii) pk[ii] = f2b(s[ii]);
  *(u16x4*)&yB[((size_t)((l * 4 + b) * 64 + o)) * 512 + j4 * 4] = pk;
}

// ---------------------------------------------------------------------------
// glu1cat
// ---------------------------------------------------------------------------
__global__ __launch_bounds__(256) void glu1cat_kernel(
    const u16* __restrict__ yB, const u16* __restrict__ g1wB,
    const float* __restrict__ g1b, u16* __restrict__ catB) {
  __shared__ u16 yL[128][72];
  const int tid = threadIdx.x, wid = tid >> 6, lane = tid & 63;
  const int l16 = lane & 15, quad = lane >> 4;
  const int l = blockIdx.x >> 4;
  const int b = (blockIdx.x >> 2) & 3;
  const int v0 = (blockIdx.x & 3) * 128;

  {
    int o = tid & 63, sv = tid >> 6;
    const u16* src = &yB[((size_t)((l * 4 + b) * 64 + o)) * 512 + v0 + sv * 32];
    u16x8 p0 = *(const u16x8*)&src[0];
    u16x8 p1 = *(const u16x8*)&src[8];
    u16x8 p2 = *(const u16x8*)&src[16];
    u16x8 p3 = *(const u16x8*)&src[24];
    #pragma unroll
    for (int ii = 0; ii < 8; ++ii) {
      yL[sv * 32 + ii][o] = p0[ii];
      yL[sv * 32 + 8 + ii][o] = p1[ii];
      yL[sv * 32 + 16 + ii][o] = p2[ii];
      yL[sv * 32 + 24 + ii][o] = p3[ii];
    }
  }
  __syncthreads();

  f32x4 acc[2][8] = {};
  #pragma unroll
  for (int ks = 0; ks < 2; ++ks) {
    short8 a0 = *(const short8*)&g1wB[l * 8192 + (wid * 16 + l16) * 64 +
                                      ks * 32 + quad * 8];
    short8 a1 = *(const short8*)&g1wB[l * 8192 + (64 + wid * 16 + l16) * 64 +
                                      ks * 32 + quad * 8];
    #pragma unroll
    for (int nb = 0; nb < 8; ++nb) {
      short8 bf = *(const short8*)&yL[nb * 16 + l16][ks * 32 + quad * 8];
      acc[0][nb] = MFMA16(a0, bf, acc[0][nb]);
      acc[1][nb] = MFMA16(a1, bf, acc[1][nb]);
    }
  }
  #pragma unroll
  for (int nb = 0; nb < 8; ++nb) {
    int v = v0 + nb * 16 + l16;
    int oc = wid * 16 + quad * 4;
    u16x4 pk;
    #pragma unroll
    for (int r = 0; r < 4; ++r) {
      float zl = acc[0][nb][r] + g1b[l * 128 + oc + r];
      float zr = acc[1][nb][r] + g1b[l * 128 + 64 + oc + r];
      pk[r] = f2b(zl * sigm(zr));
    }
    *(u16x4*)&catB[((size_t)(b * 512 + v)) * 256 + l * 64 + oc] = pk;
  }
}

// ---------------------------------------------------------------------------
// gout
// ---------------------------------------------------------------------------
__global__ __launch_bounds__(256) void gout_kernel(
    const u16* __restrict__ catB, const u16* __restrict__ gwB,
    const float* __restrict__ gb, u16* __restrict__ sB) {
  __shared__ u16 cL[64][264];
  const int tid = threadIdx.x, wid = tid >> 6, lane = tid & 63;
  const int l16 = lane & 15, quad = lane >> 4;
  const int wm = wid >> 1, wn = wid & 1;
  const int b = blockIdx.x >> 6;
  const int v0 = ((blockIdx.x >> 3) & 7) * 64;
  const int cc0 = (blockIdx.x & 7) * 32;

  {
    int v = tid >> 2, seg = (tid & 3) * 64;
    const u16* src = &catB[((size_t)(b * 512 + v0 + v)) * 256 + seg];
    #pragma unroll
    for (int s = 0; s < 8; ++s)
      *(u16x8*)&cL[v][seg + s * 8] = *(const u16x8*)&src[s * 8];
  }
  __syncthreads();

  f32x4 acc[2][2] = {};
  #pragma unroll
  for (int ks = 0; ks < 8; ++ks) {
    short8 aL = *(const short8*)&gwB[(cc0 + wm * 16 + l16) * 256 +
                                     ks * 32 + quad * 8];
    short8 aH = *(const short8*)&gwB[(256 + cc0 + wm * 16 + l16) * 256 +
                                     ks * 32 + quad * 8];
    #pragma unroll
    for (int nb = 0; nb < 2; ++nb) {
      short8 bf = *(const short8*)&cL[wn * 32 + nb * 16 + l16][ks * 32 + quad * 8];
      acc[0][nb] = MFMA16(aL, bf, acc[0][nb]);
      acc[1][nb] = MFMA16(aH, bf, acc[1][nb]);
    }
  }
  #pragma unroll
  for (int nb = 0; nb < 2; ++nb) {
    int v = v0 + wn * 32 + nb * 16 + l16;
    int cc = cc0 + wm * 16 + quad * 4;
    u16x4 pk;
    #pragma unroll
    for (int r = 0; r < 4; ++r) {
      float zl = acc[0][nb][r] + gb[cc + r];
      float zr = acc[1][nb][r] + gb[256 + cc + r];
      pk[r] = f2b(zl * sigm(zr));
    }
    *(u16x4*)&sB[((size_t)(b * 512 + v)) * 256 + cc] = pk;
  }
}

// ---------------------------------------------------------------------------
// head
// ---------------------------------------------------------------------------
__global__ __launch_bounds__(256) void head_kernel(
    const u16* __restrict__ sB, const u16* __restrict__ owB,
    const float* __restrict__ obv, float* __restrict__ out) {
  const int tid = threadIdx.x, wid = tid >> 6, lane = tid & 63;
  const int l16 = lane & 15, quad = lane >> 4;
  const int b = blockIdx.x >> 3;
  const int v0 = (blockIdx.x & 7) * 64;

  f32x4 acc = {};
  #pragma unroll
  for (int ks = 0; ks < 8; ++ks) {
    short8 a;
    if (l16 < 12) a = *(const short8*)&owB[l16 * 256 + ks * 32 + quad * 8];
    else {
      #pragma unroll
      for (int ii = 0; ii < 8; ++ii) a[ii] = 0;
    }
    short8 bf = *(const short8*)&sB[((size_t)(b * 512 + v0 + wid * 16 + l16)) * 256 +
                                    ks * 32 + quad * 8];
    acc = MFMA16(a, bf, acc);
  }
  #pragma unroll
  for (int r = 0; r < 4; ++r) {
    int p = quad * 4 + r;
    if (p < 12)
      out[(b * 12 + p) * 512 + v0 + wid * 16 + l16] = acc[r] + obv[p];
  }
}

// ---------------------------------------------------------------------------
extern "C" void kernel_launch(void* const* d_in, const int* in_sizes, int n_in,
                              void* d_out, int out_size, void* d_ws, size_t ws_size,
                              hipStream_t stream) {
  const float* x    = (const float*)d_in[0];
  const float* sape = (const float*)d_in[1];
  const float* tape = (const float*)d_in[2];
  const float* srpe = (const float*)d_in[3];
  const float* trpe = (const float*)d_in[4];
  const float* mask = (const float*)d_in[7];
  const float* Wi   = (const float*)d_in[8];
  const float* bi   = (const float*)d_in[9];
  const float* gmu  = (const float*)d_in[10];
  const float* gsg  = (const float*)d_in[11];
  const float* Wg   = (const float*)d_in[12];
  const float* bg   = (const float*)d_in[13];
  const float* Wsp  = (const float*)d_in[14];
  const float* Wtp  = (const float*)d_in[15];
  const float* fsw  = (const float*)d_in[16];
  const float* fsb  = (const float*)d_in[17];
  const float* g1w  = (const float*)d_in[18];
  const float* g1b  = (const float*)d_in[19];
  const float* gow  = (const float*)d_in[20];
  const float* gob  = (const float*)d_in[21];
  const float* ow   = (const float*)d_in[22];
  const float* obv  = (const float*)d_in[23];

  char* w = (char*)d_ws;
  u16*   hT_a = (u16*)(w + 0);            // 3,145,728 B
  u16*   hT_b = (u16*)(w + 3145728);      // 3,145,728 B
  u16*   Abf  = (u16*)(w + 6291456);      // 25,165,824 B (4 layers)
  u16*   G    = (u16*)(w + 31457280);     // 9,437,184 B
  u16*   fswT = (u16*)(w + 40894464);     // 393,216 B
  u16*   WgT  = (u16*)(w + 41287680);     // 65,536 B
  u16*   g1wB = (u16*)(w + 41353216);     // 65,536 B
  u16*   gwB  = (u16*)(w + 41418752);     // 262,144 B
  u16*   owB  = (u16*)(w + 41680896);     // 8,192 B
  float* spb  = (float*)(w + 41689088);   // 1,048,576 B
  float* tpb  = (float*)(w + 42737664);   // 98,304 B
  float* ev   = (float*)(w + 42835968);   // 16,384 B
  u16*   ypt  = (u16*)(w + 42852352);     // 12,582,912 B (4 x 1,572,864 u16)
  u16*   yB   = (u16*)(w + 55435264);     // 2,097,152 B
  u16*   catB = (u16*)(w + 57532416);     // 1,048,576 B
  u16*   sB   = (u16*)(w + 58580992);     // 1,048,576 B

  prep_kernel<<<4463, 256, 0, stream>>>(x, sape, tape, srpe, trpe, Wi, bi, gmu, gsg,
                                        Wg, bg, Wsp, Wtp, fsw, mask, g1w, gow, ow,
                                        hT_a, Abf, spb, tpb, fswT, WgT, ev,
                                        g1wB, gwB, owB);
  u16* hin = hT_a;
  u16* hout = hT_b;
  for (int l = 0; l < 4; ++l) {
    agg_kernel<<<288, 256, 0, stream>>>(Abf + (size_t)l * 3145728, hin, G);
    combine_kernel<<<192, 256, 0, stream>>>(G, ev + l * 144, WgT + l * 8192,
                                            spb + l * 65536, tpb + l * 6144,
                                            fswT + l * 49152, hout,
                                            ypt + (size_t)l * 1572864);
    u16* tmp = hin; hin = hout; hout = tmp;
  }
  reduce_kernel<<<512, 256, 0, stream>>>(ypt, fsb, yB);
  glu1cat_kernel<<<64, 256, 0, stream>>>(yB, g1wB, g1b, catB);
  gout_kernel<<<256, 256, 0, stream>>>(catB, gwB, gob, sB);
  head_kernel<<<32, 256, 0, stream>>>(sB, owB, obv, (float*)d_out);
}